// Round 11
// baseline (4293.447 us; speedup 1.0000x reference)
//
#include <hip/hip_runtime.h>
#include <stdint.h>

// LSTM: V=50000, D=256, H=512, B=64, T=512. out = stack([c_final, h_final]) fp32 [2,64,512]
//
// R14: two phase-shifted batch-sets inside the PROVEN R11 envelope.
//   Sets A = batches 0-31, B = 32-63 are independent recurrences. Each wave
//   alternates slots A(t), B(t): while one set's flag/h round-trips fly, the
//   wave computes the other set's MFMAs/epilogue/store. Check-then-load order
//   kept (flags_s' checked BEFORE issuing s' h-loads) => sound.
//   - Same Wlds (48 KB, W shared by both sets), same flag region (A at +0,
//     B at +64B of each wave's 128B line), same hb0/hb1, same ws extent 164352.
//   - Slot: drain -> x-MFMA -> pre-issue poll -> h-MFMA -> epilogue -> check
//     (retry rare) -> store h(t+1) -> issue next set's x+h+wi loads -> counted
//     vmcnt retires store -> post flag. All RTs ~1 slot old when consumed.
//   - Coop launch + PLAIN-LAUNCH FALLBACK if coop returns error (64 WGs at
//     1 WG/CU are co-resident regardless; spin-flags tolerate dispatch order).

#define NWG     64
#define NTHR    256
#define TSTEPS  512
#define BATCH   64
#define EDIM    256
#define HID     512
#define GCOLS   2048

typedef __attribute__((ext_vector_type(8))) short short8;
typedef __attribute__((ext_vector_type(4))) float f32x4;

// ws layout (PROVEN extent [0, 164352)):
//   256    : flags, 64 WG x 4 waves x 128 B lines (A-flag +0, B-flag +64B)
//   33280  : hb0 [64][512] bf16 (rows 0-31 = set A, 32-63 = set B)
//   98816  : hb1 [64][512] bf16

__device__ __forceinline__ unsigned short f2bf(float f) {
  unsigned u = __float_as_uint(f);
  unsigned r = (u + 0x7FFFu + ((u >> 16) & 1u)) >> 16;  // RNE
  return (unsigned short)r;
}
__device__ __forceinline__ float sigf(float x) {
  x = fminf(fmaxf(x, -30.0f), 30.0f);
  return 1.0f / (1.0f + __expf(-x));
}
__device__ __forceinline__ float tanh_fast(float x) {
  x = fminf(fmaxf(x, -15.0f), 15.0f);
  float e = __expf(-2.0f * x);
  return (1.0f - e) / (1.0f + e);
}
__device__ __forceinline__ void lstm_cell(float gi, float gj, float gf, float go,
                                          int t, int nw, float& c, float& h) {
  float cn = sigf(gf + 1.0f) * c + sigf(gi) * tanh_fast(gj);  // FORGET_BIAS=1
  float hn = sigf(go) * tanh_fast(cn);
  if (t < nw) { c = cn; h = hn; }      // static_rnn: copy state through past end
}

__global__ void init_ws(unsigned* ws, int nwords) {
  int i = blockIdx.x * 256 + threadIdx.x;
  if (i < nwords) ws[i] = 0u;
}

__launch_bounds__(NTHR, 1)
__global__ void lstm_persist(const int* __restrict__ num_words,
                             const int* __restrict__ widx,
                             const float* __restrict__ Wemb,
                             const float* __restrict__ Wk,
                             const float* __restrict__ bias,
                             unsigned short* __restrict__ hb0,
                             unsigned short* __restrict__ hb1,
                             unsigned* flags,
                             float* __restrict__ out)
{
  // B-fragment-ordered W strip (R3/R9/R11-proven layout)
  __shared__ alignas(16) short Wlds[24576];            // 48 KB
  __shared__ alignas(16) unsigned short hstg[256];     // per-wave 8x8 h tile

  const int tid  = threadIdx.x;
  const int lane = tid & 63;
  const int wv   = tid >> 6;
  const int u0   = blockIdx.x * 8;               // this WG's hidden units u0..u0+7

  for (int q = tid; q < 3072; q += NTHR) {
    int lq = q & 63;
    int kkn = q >> 6;                            // 0..47
    int nt = (kkn >= 24) ? 1 : 0;
    int kk = kkn - nt * 24;
    int kbase = kk * 32 + ((lq >> 4) << 3);
    int nn = (nt << 4) + (lq & 15);
    int gcol = ((nn >> 3) << 9) + u0 + (nn & 7); // gate g -> cols g*512 + unit
    short8 v;
#pragma unroll
    for (int j = 0; j < 8; ++j)
      v[j] = (short)f2bf(Wk[(size_t)(kbase + j) * GCOLS + gcol]);
    *(short8*)&Wlds[q * 8] = v;
  }

  // MFMA geometry: 16-row M tile; rows 0-7 real, 8-15 duplicates (8 batches/set/wave)
  const int n   = lane & 15;                     // C col: gate pair + unit
  const int q4  = lane >> 4;                     // row quarter
  const int kq  = q4 << 3;                       // k sub-offset 0/8/16/24
  const int un  = n & 7;                         // unit within WG
  const bool lo = (n < 8);                       // lanes holding gates (i,f); hi = (j,o)
  const int bbA = wv * 8 + (n & 7);              // set-A batch row this lane loads
  const int bbB = 32 + bbA;                      // set-B batch row

  float bias_g[4];
#pragma unroll
  for (int g = 0; g < 4; ++g) bias_g[g] = bias[g * HID + u0 + un];
  int nwA[4], nwB[4];
#pragma unroll
  for (int r = 0; r < 4; ++r) {
    int row = ((q4 << 2) + r) & 7;
    nwA[r] = num_words[wv * 8 + row];
    nwB[r] = num_words[32 + wv * 8 + row];
  }

  float cA[4] = {0,0,0,0}, hA[4] = {0,0,0,0};
  float cB[4] = {0,0,0,0}, hB[4] = {0,0,0,0};

  unsigned* myflagA = flags + ((blockIdx.x << 2) + wv) * 32;     // this wave's line
  unsigned* myflagB = myflagA + 16;                              // +64 B
  const unsigned* fpA = flags + ((lane << 2) + wv) * 32;         // lane l: WG l, wave wv
  const unsigned* fpB = fpA + 16;

  unsigned short* hb[2] = {hb0, hb1};

  float4 pfw[16];          // x row slice for the NEXT slot's set
  uint4  av[16];           // h row slice for the NEXT slot's set
  int wiA, wiB;
  {
    int wi0 = widx[bbA * TSTEPS + 0];            // preload x_A(0)
    const float* er = Wemb + (size_t)wi0 * EDIM + kq;
#pragma unroll
    for (int kk = 0; kk < 8; ++kk) {
      pfw[2 * kk]     = *(const float4*)(er + kk * 32);
      pfw[2 * kk + 1] = *(const float4*)(er + kk * 32 + 4);
    }
    wiA = widx[bbA * TSTEPS + 1];                // for x_A(1) issue at B(0)
    wiB = widx[bbB * TSTEPS + 0];                // for x_B(0) issue at A(0)
  }

  __syncthreads();                               // Wlds ready (setup only)
  asm volatile("s_waitcnt vmcnt(0)" ::: "memory");
  __builtin_amdgcn_sched_barrier(0);

  for (int t = 0; t < TSTEPS; ++t) {
    // ================= SLOT A: set A, step t =================
    {
      asm volatile("s_waitcnt vmcnt(0)" ::: "memory");   // pfw=x_A(t), av=h_A(t) ready
      __builtin_amdgcn_sched_barrier(0);
      f32x4 acc0 = {0,0,0,0}, acc1 = {0,0,0,0};
#pragma unroll
      for (int kk = 0; kk < 8; ++kk) {                   // x-MFMAs
        float4 f0 = pfw[2 * kk], f1 = pfw[2 * kk + 1];
        short8 a;
        a[0]=(short)f2bf(f0.x); a[1]=(short)f2bf(f0.y);
        a[2]=(short)f2bf(f0.z); a[3]=(short)f2bf(f0.w);
        a[4]=(short)f2bf(f1.x); a[5]=(short)f2bf(f1.y);
        a[6]=(short)f2bf(f1.z); a[7]=(short)f2bf(f1.w);
        acc0 = __builtin_amdgcn_mfma_f32_16x16x32_bf16(a, *(const short8*)&Wlds[((kk)*64+lane)*8],      acc0, 0,0,0);
        acc1 = __builtin_amdgcn_mfma_f32_16x16x32_bf16(a, *(const short8*)&Wlds[((24+kk)*64+lane)*8],   acc1, 0,0,0);
      }
      unsigned fv = 0xFFFFFFFFu;                         // pre-issue poll: flags_B >= t
      if (t > 0)
        asm volatile("global_load_dword %0, %1, off sc0 sc1" : "=v"(fv) : "v"(fpB));
      if (t > 0) {
#pragma unroll
        for (int kk = 0; kk < 16; ++kk) {                // h-MFMAs
          short8 a = __builtin_bit_cast(short8, av[kk]);
          acc0 = __builtin_amdgcn_mfma_f32_16x16x32_bf16(a, *(const short8*)&Wlds[((8+kk)*64+lane)*8],  acc0, 0,0,0);
          acc1 = __builtin_amdgcn_mfma_f32_16x16x32_bf16(a, *(const short8*)&Wlds[((32+kk)*64+lane)*8], acc1, 0,0,0);
        }
      }
#pragma unroll
      for (int r = 0; r < 4; ++r) {                      // epilogue A
        float a0o = acc0[r], a1o = acc1[r];
        float a0x = __shfl_xor(a0o, 8), a1x = __shfl_xor(a1o, 8);
        float gi = lo ? a0o : a0x, gj = lo ? a0x : a0o;
        float gf = lo ? a1o : a1x, go = lo ? a1x : a1o;
        lstm_cell(gi + bias_g[0], gj + bias_g[1], gf + bias_g[2], go + bias_g[3],
                  t, nwA[r], cA[r], hA[r]);
      }
      if (lo && q4 < 2) {                                // pack 8x8 tile
#pragma unroll
        for (int r = 0; r < 4; ++r)
          hstg[wv * 64 + ((q4 << 2) + r) * 8 + un] = f2bf(hA[r]);
      }
      asm volatile("s_waitcnt lgkmcnt(0)" ::: "memory");
      if (t > 0) {                                       // check flags_B >= t
        asm volatile("s_waitcnt vmcnt(0)" ::: "memory");
        __builtin_amdgcn_sched_barrier(0);
        const unsigned tgt = (unsigned)t;
        int tries = 0;
        while (__ballot(fv >= tgt) != ~0ull) {
          if (++tries > (1 << 20)) break;
          asm volatile("global_load_dword %0, %1, off sc0 sc1\n\t"
                       "s_waitcnt vmcnt(0)" : "=v"(fv) : "v"(fpB));
          __builtin_amdgcn_sched_barrier(0);
        }
      }
      const bool dostore = (t + 1 < TSTEPS);             // h_A(t+1) consumed at A(t+1)
      if (dostore && lane < 32) {
        int row = lane >> 2, p = lane & 3;
        unsigned hv = *(const unsigned*)&hstg[wv * 64 + row * 8 + p * 2];
        unsigned* dst = (unsigned*)(hb[(t+1)&1] + (size_t)(wv*8+row)*HID + u0) + p;
        asm volatile("global_store_dword %0, %1, off sc0 sc1" :: "v"(dst), "v"(hv) : "memory");
      }
      {                                                  // issue loads for B(t)
        const float* er = Wemb + (size_t)wiB * EDIM + kq;
#pragma unroll
        for (int kk = 0; kk < 8; ++kk) {
          asm volatile("global_load_dwordx4 %0, %1, off" : "=v"(pfw[2*kk])   : "v"(er + kk*32));
          asm volatile("global_load_dwordx4 %0, %1, off" : "=v"(pfw[2*kk+1]) : "v"(er + kk*32 + 4));
        }
        if (t > 0) {
          const unsigned short* hr = hb[t & 1] + (size_t)bbB * HID + kq;
#pragma unroll
          for (int kk = 0; kk < 16; ++kk)
            asm volatile("global_load_dwordx4 %0, %1, off sc0 sc1" : "=v"(av[kk]) : "v"(hr + kk*32));
        }
        const int* wp = widx + bbB * TSTEPS + ((t+1 < TSTEPS) ? t+1 : TSTEPS-1);
        asm volatile("global_load_dword %0, %1, off" : "=v"(wiB) : "v"(wp));
      }
      if (dostore) {
        if (t > 0) asm volatile("s_waitcnt vmcnt(33)" ::: "memory");  // retires store
        else       asm volatile("s_waitcnt vmcnt(17)" ::: "memory");
        if (lane == 0) {
          unsigned fvw = (unsigned)(t + 1);
          asm volatile("global_store_dword %0, %1, off sc0 sc1" :: "v"(myflagA), "v"(fvw) : "memory");
        }
      }
    }
    // ================= SLOT B: set B, step t =================
    {
      asm volatile("s_waitcnt vmcnt(0)" ::: "memory");   // pfw=x_B(t), av=h_B(t) ready
      __builtin_amdgcn_sched_barrier(0);
      f32x4 acc0 = {0,0,0,0}, acc1 = {0,0,0,0};
#pragma unroll
      for (int kk = 0; kk < 8; ++kk) {                   // x-MFMAs
        float4 f0 = pfw[2 * kk], f1 = pfw[2 * kk + 1];
        short8 a;
        a[0]=(short)f2bf(f0.x); a[1]=(short)f2bf(f0.y);
        a[2]=(short)f2bf(f0.z); a[3]=(short)f2bf(f0.w);
        a[4]=(short)f2bf(f1.x); a[5]=(short)f2bf(f1.y);
        a[6]=(short)f2bf(f1.z); a[7]=(short)f2bf(f1.w);
        acc0 = __builtin_amdgcn_mfma_f32_16x16x32_bf16(a, *(const short8*)&Wlds[((kk)*64+lane)*8],      acc0, 0,0,0);
        acc1 = __builtin_amdgcn_mfma_f32_16x16x32_bf16(a, *(const short8*)&Wlds[((24+kk)*64+lane)*8],   acc1, 0,0,0);
      }
      unsigned fv = 0xFFFFFFFFu;                         // pre-issue poll: flags_A >= t+1
      const bool more = (t + 1 < TSTEPS);
      if (more)
        asm volatile("global_load_dword %0, %1, off sc0 sc1" : "=v"(fv) : "v"(fpA));
      if (t > 0) {
#pragma unroll
        for (int kk = 0; kk < 16; ++kk) {                // h-MFMAs
          short8 a = __builtin_bit_cast(short8, av[kk]);
          acc0 = __builtin_amdgcn_mfma_f32_16x16x32_bf16(a, *(const short8*)&Wlds[((8+kk)*64+lane)*8],  acc0, 0,0,0);
          acc1 = __builtin_amdgcn_mfma_f32_16x16x32_bf16(a, *(const short8*)&Wlds[((32+kk)*64+lane)*8], acc1, 0,0,0);
        }
      }
#pragma unroll
      for (int r = 0; r < 4; ++r) {                      // epilogue B
        float a0o = acc0[r], a1o = acc1[r];
        float a0x = __shfl_xor(a0o, 8), a1x = __shfl_xor(a1o, 8);
        float gi = lo ? a0o : a0x, gj = lo ? a0x : a0o;
        float gf = lo ? a1o : a1x, go = lo ? a1x : a1o;
        lstm_cell(gi + bias_g[0], gj + bias_g[1], gf + bias_g[2], go + bias_g[3],
                  t, nwB[r], cB[r], hB[r]);
      }
      if (more) {
        if (lo && q4 < 2) {                              // pack 8x8 tile
#pragma unroll
          for (int r = 0; r < 4; ++r)
            hstg[wv * 64 + ((q4 << 2) + r) * 8 + un] = f2bf(hB[r]);
        }
        asm volatile("s_waitcnt lgkmcnt(0)" ::: "memory");
        {                                                // check flags_A >= t+1
          asm volatile("s_waitcnt vmcnt(0)" ::: "memory");
          __builtin_amdgcn_sched_barrier(0);
          const unsigned tgt = (unsigned)(t + 1);
          int tries = 0;
          while (__ballot(fv >= tgt) != ~0ull) {
            if (++tries > (1 << 20)) break;
            asm volatile("global_load_dword %0, %1, off sc0 sc1\n\t"
                         "s_waitcnt vmcnt(0)" : "=v"(fv) : "v"(fpA));
            __builtin_amdgcn_sched_barrier(0);
          }
        }
        if (lane < 32) {                                 // store h_B(t+1)
          int row = lane >> 2, p = lane & 3;
          unsigned hv = *(const unsigned*)&hstg[wv * 64 + row * 8 + p * 2];
          unsigned* dst = (unsigned*)(hb[(t+1)&1] + (size_t)(32+wv*8+row)*HID + u0) + p;
          asm volatile("global_store_dword %0, %1, off sc0 sc1" :: "v"(dst), "v"(hv) : "memory");
        }
        {                                                // issue loads for A(t+1)
          const float* er = Wemb + (size_t)wiA * EDIM + kq;
#pragma unroll
          for (int kk = 0; kk < 8; ++kk) {
            asm volatile("global_load_dwordx4 %0, %1, off" : "=v"(pfw[2*kk])   : "v"(er + kk*32));
            asm volatile("global_load_dwordx4 %0, %1, off" : "=v"(pfw[2*kk+1]) : "v"(er + kk*32 + 4));
          }
          const unsigned short* hr = hb[(t+1) & 1] + (size_t)bbA * HID + kq;
#pragma unroll
          for (int kk = 0; kk < 16; ++kk)
            asm volatile("global_load_dwordx4 %0, %1, off sc0 sc1" : "=v"(av[kk]) : "v"(hr + kk*32));
          const int* wp = widx + bbA * TSTEPS + ((t+2 < TSTEPS) ? t+2 : TSTEPS-1);
          asm volatile("global_load_dword %0, %1, off" : "=v"(wiA) : "v"(wp));
        }
        asm volatile("s_waitcnt vmcnt(33)" ::: "memory");   // retires h_B store
        if (lane == 0) {
          unsigned fvw = (unsigned)(t + 1);
          asm volatile("global_store_dword %0, %1, off sc0 sc1" :: "v"(myflagB), "v"(fvw) : "memory");
        }
      }
    }
  }

  asm volatile("s_waitcnt vmcnt(0)" ::: "memory");
  __builtin_amdgcn_sched_barrier(0);

  // ---- final state: out[0][b][h]=c, out[1][b][h]=h (both sets) ----
  if (lo && q4 < 2) {
#pragma unroll
    for (int r = 0; r < 4; ++r) {
      int row = (q4 << 2) + r;
      int bA = wv * 8 + row, bB = bA + 32;
      out[bA * HID + u0 + un]               = cA[r];
      out[BATCH * HID + bA * HID + u0 + un] = hA[r];
      out[bB * HID + u0 + un]               = cB[r];
      out[BATCH * HID + bB * HID + u0 + un] = hB[r];
    }
  }
}

extern "C" void kernel_launch(void* const* d_in, const int* in_sizes, int n_in,
                              void* d_out, int out_size, void* d_ws, size_t ws_size,
                              hipStream_t stream) {
  const int*   widx = (const int*)d_in[0];
  const int*   nw   = (const int*)d_in[1];
  const float* Wemb = (const float*)d_in[2];
  const float* Wk   = (const float*)d_in[3];
  const float* bias = (const float*)d_in[4];
  float* out = (float*)d_out;
  char* ws = (char*)d_ws;

  unsigned* flags     = (unsigned*)(ws + 256);
  unsigned short* hb0 = (unsigned short*)(ws + 33280);
  unsigned short* hb1 = (unsigned short*)(ws + 98816);

  const int init_words = 164352 / 4;  // flags + both h buffers (PROVEN extent)
  init_ws<<<(init_words + 255) / 256, 256, 0, stream>>>((unsigned*)ws, init_words);

  void* args[] = {(void*)&nw, (void*)&widx, (void*)&Wemb, (void*)&Wk, (void*)&bias,
                  (void*)&hb0, (void*)&hb1, (void*)&flags, (void*)&out};
  hipError_t e = hipLaunchCooperativeKernel((void*)lstm_persist, dim3(NWG), dim3(NTHR),
                                            args, 0, stream);
  if (e != hipSuccess) {
    // fallback: plain launch; 64 WGs at 1 WG/CU are co-resident on 256 CUs,
    // and the flag protocol tolerates any dispatch order.
    lstm_persist<<<dim3(NWG), dim3(NTHR), 0, stream>>>(
        nw, widx, Wemb, Wk, bias, hb0, hb1, flags, out);
  }
}